// Round 3
// baseline (23.830 us; speedup 1.0000x reference)
//
#include <hip/hip_runtime.h>

#define NC 256   // channels
#define NK 16    // cluster centers

// Bit-exact replica of the reference's per-element assignment for ANY t:
// scan k ascending, strict <  -> first index wins ties (jnp.argmin semantics).
__device__ __forceinline__ float argmin16(float t, const float* cen) {
    float best = 3.4e38f;
    float bc = 0.0f;
#pragma unroll
    for (int k = 0; k < NK; ++k) {
        float d = fabsf(t - cen[k]);
        bool p = d < best;
        best = p ? d : best;
        bc   = p ? cen[k] : bc;
    }
    return bc;
}

__global__ __launch_bounds__(256) void lutfq_kernel(
    const float4* __restrict__ x,
    const float*  __restrict__ scales,
    const float*  __restrict__ centers,
    float4*       __restrict__ out,
    int n4)
{
    // 512-bucket LUT over u2 = 2t; bucket ub covers u2 in [ub-256, ub-255).
    // Decision midpoints of integer centers are half-integers = bucket edges,
    // so the assignment is constant on every bucket interior.
    __shared__ float s_lut[512];

    float cen[NK];
#pragma unroll
    for (int k = 0; k < NK; ++k) cen[k] = rintf(centers[k]);  // round-half-to-even == jnp.round

    const int tid = threadIdx.x;

    // Buckets 0 and 510 are built at their LEFT edge (t = -128.0 / 127.0).
    // Those points are provably not midpoints of distinct integer centers in
    // [-128,127] (c1+c2 = -256 or 254 is impossible), so argmin is constant on
    // the closed-left bucket — this serves the clip masses exactly, no fallback.
    for (int ub = tid; ub < 512; ub += 256) {
        float t;
        if (ub == 0)        t = -128.0f;
        else if (ub >= 510) t = 127.0f;
        else                t = 0.5f * (float)(ub - 256) + 0.25f;  // interior rep
        s_lut[ub] = argmin16(t, cen);
    }

    // Per-thread channels are loop-invariant: i mod 64 == tid mod 64, since
    // blockDim (256) and the grid stride are multiples of 64. Load scales once.
    const int c4 = (tid & 63) * 4;
    const float4 sv = *reinterpret_cast<const float4*>(&scales[c4]);
    float sj[4]   = { sv.x, sv.y, sv.z, sv.w };
    float den[4], r256[4], so[4];
#pragma unroll
    for (int j = 0; j < 4; ++j) {
        den[j]  = sj[j] + 1e-8f;        // ref's denominator
        r256[j] = 256.0f / den[j];      // fast-path reciprocal (<=1 ulp on u2)
        so[j]   = sj[j] * 0.0078125f;   // s/128, exact
    }
    __syncthreads();

    const int stride = gridDim.x * blockDim.x;
    for (int i = blockIdx.x * blockDim.x + tid; i < n4; i += stride) {
        float4 xv = x[i];
        float xin[4] = { xv.x, xv.y, xv.z, xv.w };
        float rv[4];

#pragma unroll
        for (int j = 0; j < 4; ++j) {
            // u2 = 2 * clip(x/(s+eps)*128, -128, 127), computed as one mul.
            // (x * r256 == 2 * (x * r128) exactly; clamp commutes with pow2 scale.)
            float u2 = xin[j] * r256[j];
            u2 = fminf(fmaxf(u2, -256.0f), 254.0f);

            float fl   = floorf(u2);      // exact
            float frac = u2 - fl;         // (near-)exact; only used for band test
            int   ub   = (int)fl + 256;   // 0..510

            float c = s_lut[ub];

            // Fallback zone: within 2^-12 of a bucket edge (covers both the
            // reciprocal's <=2^-15 error and the ref's rounded-distance tie
            // band), excluding the provably-safe clamp rails. ~5e-4 of elements.
            bool band = (frac < 0x1p-12f) | (frac > 1.0f - 0x1p-12f);
            bool rail = (u2 == -256.0f) | (u2 == 254.0f);
            if (band && !rail) {
                float t = (xin[j] / den[j]) * 128.0f;   // exact ref arithmetic
                t = fminf(fmaxf(t, -128.0f), 127.0f);
                c = argmin16(t, cen);                   // bit-exact ref replay
            }

            rv[j] = c * so[j];   // c*(s/128) == (c/128)*s bit-exactly
        }

        float4 r; r.x = rv[0]; r.y = rv[1]; r.z = rv[2]; r.w = rv[3];
        out[i] = r;
    }
}

extern "C" void kernel_launch(void* const* d_in, const int* in_sizes, int n_in,
                              void* d_out, int out_size, void* d_ws, size_t ws_size,
                              hipStream_t stream) {
    const float* x       = (const float*)d_in[0];
    const float* scales  = (const float*)d_in[1];
    const float* centers = (const float*)d_in[2];
    float* out = (float*)d_out;

    int n4 = out_size / 4;
    int blocks = (n4 + 255) / 256;
    if (blocks > 2048) blocks = 2048;  // grid-stride; ~8 blocks/CU

    lutfq_kernel<<<blocks, 256, 0, stream>>>(
        (const float4*)x, scales, centers, (float4*)out, n4);
}

// Round 5
// 23.724 us; speedup vs baseline: 1.0045x; 1.0045x over previous
//
#include <hip/hip_runtime.h>

#define NC 256   // channels
#define NK 16    // cluster centers

// Native clang vector type: accepted by __builtin_nontemporal_load/store
// (HIP_vector_type float4 is a struct and is rejected).
typedef float f32x4 __attribute__((ext_vector_type(4)));

// Bit-exact replica of the reference's per-element assignment for ANY t:
// scan k ascending, strict <  -> first index wins ties (jnp.argmin semantics).
__device__ __forceinline__ float argmin16(float t, const float* cen) {
    float best = 3.4e38f;
    float bc = 0.0f;
#pragma unroll
    for (int k = 0; k < NK; ++k) {
        float d = fabsf(t - cen[k]);
        bool p = d < best;
        best = p ? d : best;
        bc   = p ? cen[k] : bc;
    }
    return bc;
}

__global__ __launch_bounds__(256) void lutfq_kernel(
    const f32x4* __restrict__ x,
    const float* __restrict__ scales,
    const float* __restrict__ centers,
    f32x4*       __restrict__ out,
    int n4)
{
    // 512-bucket LUT over u2 = 2t; bucket ub covers u2 in [ub-256, ub-255).
    // Integer centers -> decision midpoints are half-integers = bucket edges,
    // so the assignment is constant on every bucket interior.
    __shared__ float s_lut[512];

    float cen[NK];
#pragma unroll
    for (int k = 0; k < NK; ++k) cen[k] = rintf(centers[k]);  // round-half-to-even == jnp.round

    const int tid = threadIdx.x;

    // Buckets 0 and 510 built at their LEFT edge (t = -128.0 / 127.0): those
    // points are provably not midpoints of distinct integer centers in
    // [-128,127], so the closed-left bucket is constant -> clip masses are
    // served exactly with no fallback.
    for (int ub = tid; ub < 512; ub += 256) {
        float t;
        if (ub == 0)        t = -128.0f;
        else if (ub >= 510) t = 127.0f;
        else                t = 0.5f * (float)(ub - 256) + 0.25f;  // interior rep
        s_lut[ub] = argmin16(t, cen);
    }

    // Per-thread channels are grid-stride-invariant (stride % 64 == 0):
    // load the 4 owned scales once into registers.
    const int c4 = (tid & 63) * 4;
    const f32x4 sv = *reinterpret_cast<const f32x4*>(&scales[c4]);
    float den[4], r256[4], so[4];
#pragma unroll
    for (int j = 0; j < 4; ++j) {
        float s = sv[j];
        den[j]  = s + 1e-8f;        // ref's denominator
        r256[j] = 256.0f / den[j];  // fast-path reciprocal (<=1 ulp on u2)
        so[j]   = s * 0.0078125f;   // s/128, exact
    }
    __syncthreads();

    const int stride = gridDim.x * blockDim.x;

    auto process = [&](f32x4 xv) -> f32x4 {
        f32x4 r;
#pragma unroll
        for (int j = 0; j < 4; ++j) {
            // u2 = 2 * clip(x/(s+eps)*128, -128, 127) as one mul + clamp.
            float u2 = xv[j] * r256[j];
            u2 = fminf(fmaxf(u2, -256.0f), 254.0f);

            float fl   = floorf(u2);      // exact
            float frac = u2 - fl;         // only used for band test
            int   ub   = (int)fl + 256;   // 0..510

            float c = s_lut[ub];

            // Within 2^-12 of a bucket edge (covers the reciprocal's <=2^-15
            // error and the ref's rounded-distance tie band), excluding the
            // provably-safe clamp rails: replay exact ref arithmetic. ~5e-4.
            bool band = (frac < 0x1p-12f) | (frac > 1.0f - 0x1p-12f);
            bool rail = (u2 == -256.0f) | (u2 == 254.0f);
            if (band && !rail) {
                float t = (xv[j] / den[j]) * 128.0f;    // exact ref arithmetic
                t = fminf(fmaxf(t, -128.0f), 127.0f);
                c = argmin16(t, cen);                   // bit-exact ref replay
            }
            r[j] = c * so[j];   // c*(s/128) == (c/128)*s bit-exactly
        }
        return r;
    };

    // Unroll x2: two nontemporal b128 loads in flight, nontemporal stores.
    // nt bypasses L2 allocation -> no read-for-ownership on the write stream.
    int i = blockIdx.x * blockDim.x + tid;
    for (; i + stride < n4; i += 2 * stride) {
        f32x4 a = __builtin_nontemporal_load(&x[i]);
        f32x4 b = __builtin_nontemporal_load(&x[i + stride]);
        f32x4 ra = process(a);
        f32x4 rb = process(b);
        __builtin_nontemporal_store(ra, &out[i]);
        __builtin_nontemporal_store(rb, &out[i + stride]);
    }
    if (i < n4) {
        f32x4 a = __builtin_nontemporal_load(&x[i]);
        __builtin_nontemporal_store(process(a), &out[i]);
    }
}

extern "C" void kernel_launch(void* const* d_in, const int* in_sizes, int n_in,
                              void* d_out, int out_size, void* d_ws, size_t ws_size,
                              hipStream_t stream) {
    const float* x       = (const float*)d_in[0];
    const float* scales  = (const float*)d_in[1];
    const float* centers = (const float*)d_in[2];
    float* out = (float*)d_out;

    int n4 = out_size / 4;
    int blocks = (n4 + 255) / 256;
    if (blocks > 2048) blocks = 2048;  // 8192 waves = exactly fills 256 CUs x 32

    lutfq_kernel<<<blocks, 256, 0, stream>>>(
        (const f32x4*)x, scales, centers, (f32x4*)out, n4);
}